// Round 1
// baseline (241.126 us; speedup 1.0000x reference)
//
#include <hip/hip_runtime.h>
#include <hip/hip_bf16.h>
#include <stdint.h>

// Problem constants
#define Bn 4
#define LQ 1024
#define LK 2048
#define DQ 1024
#define DK 512
#define DV 512
#define Dm 1024
#define Hn 16
#define HD 64

typedef __attribute__((ext_vector_type(4))) float f32x4;
typedef __attribute__((ext_vector_type(8))) short bf16x8;

__device__ __forceinline__ ushort f2bf(float f) {
  union { float f; uint32_t u; } v; v.f = f;
  uint32_t r = v.u + 0x7FFF + ((v.u >> 16) & 1);
  return (ushort)(r >> 16);
}

__device__ __forceinline__ void gload16(const void* g, void* lds) {
  __builtin_amdgcn_global_load_lds(
      (const __attribute__((address_space(1))) void*)g,
      (__attribute__((address_space(3))) void*)lds, 16, 0, 0);
}

// ---------------- weight transpose + cast: W[K][N] f32 -> Wt[N][K] bf16 ----------------
__global__ __launch_bounds__(256) void transpose_cast_kernel(
    const float* __restrict__ W, ushort* __restrict__ Wt, int K, int N) {
  __shared__ float tile[64][65];
  int k0 = blockIdx.x * 64, n0 = blockIdx.y * 64;
  int tx = threadIdx.x & 63, ty = threadIdx.x >> 6;
#pragma unroll
  for (int i = 0; i < 16; ++i) {
    int r = ty + i * 4;
    tile[r][tx] = W[(size_t)(k0 + r) * N + n0 + tx];
  }
  __syncthreads();
#pragma unroll
  for (int i = 0; i < 16; ++i) {
    int r = ty + i * 4;
    Wt[(size_t)(n0 + r) * K + k0 + tx] = f2bf(tile[tx][r]);
  }
}

// ---------------- elementwise f32 -> bf16 cast ----------------
__global__ __launch_bounds__(256) void cast_bf16_kernel(
    const float4* __restrict__ in, ushort4* __restrict__ out, int n4) {
  int i = blockIdx.x * blockDim.x + threadIdx.x;
  int stride = gridDim.x * blockDim.x;
  for (; i < n4; i += stride) {
    float4 v = in[i];
    out[i] = make_ushort4(f2bf(v.x), f2bf(v.y), f2bf(v.z), f2bf(v.w));
  }
}

// ---------------- LayerNorm over D=1024, f32 in -> bf16 out ----------------
__global__ __launch_bounds__(256) void ln_kernel(
    const float* __restrict__ x, const float* __restrict__ g,
    const float* __restrict__ b, ushort* __restrict__ y) {
  int row = blockIdx.x;
  const float4* xr = (const float4*)(x + (size_t)row * 1024);
  float4 v = xr[threadIdx.x];
  float s1 = v.x + v.y + v.z + v.w;
  float s2 = v.x * v.x + v.y * v.y + v.z * v.z + v.w * v.w;
#pragma unroll
  for (int off = 32; off > 0; off >>= 1) {
    s1 += __shfl_down(s1, off);
    s2 += __shfl_down(s2, off);
  }
  __shared__ float r1[4], r2[4];
  int w = threadIdx.x >> 6, lane = threadIdx.x & 63;
  if (lane == 0) { r1[w] = s1; r2[w] = s2; }
  __syncthreads();
  s1 = r1[0] + r1[1] + r1[2] + r1[3];
  s2 = r2[0] + r2[1] + r2[2] + r2[3];
  float mu = s1 * (1.0f / 1024.0f);
  float var = s2 * (1.0f / 1024.0f) - mu * mu;
  float rstd = rsqrtf(var + 1e-5f);
  float4 gv = ((const float4*)g)[threadIdx.x];
  float4 bv = ((const float4*)b)[threadIdx.x];
  ushort4 o;
  o.x = f2bf((v.x - mu) * rstd * gv.x + bv.x);
  o.y = f2bf((v.y - mu) * rstd * gv.y + bv.y);
  o.z = f2bf((v.z - mu) * rstd * gv.z + bv.z);
  o.w = f2bf((v.w - mu) * rstd * gv.w + bv.w);
  ((ushort4*)(y + (size_t)row * 1024))[threadIdx.x] = o;
}

// ---------------- GEMM: C[M][N] = A[M][K](bf16) @ Bt[N][K]^T(bf16) + bias ----------------
// EPI 0: bf16 row-major out.  EPI 1: bf16 out scattered to Vt[(b*16+h)*64+hd][LK].
// EPI 2: f32 out + residual.
template <int EPI>
__global__ __launch_bounds__(256) void gemm_bt_kernel(
    const ushort* __restrict__ A, const ushort* __restrict__ Bt,
    const float* __restrict__ bias, void* __restrict__ Cout,
    const float* __restrict__ residual, int M, int N, int K) {
  __shared__ ushort As[128 * 32];
  __shared__ ushort Bs[128 * 32];
  const int t = threadIdx.x;
  const int lane = t & 63;
  const int w = t >> 6;
  const int wm = w >> 1, wn = w & 1;
  const int m0 = blockIdx.y * 128, n0 = blockIdx.x * 128;
  const int l15 = lane & 15, g = lane >> 4;

  f32x4 acc[4][4] = {};

  for (int kt = 0; kt < K; kt += 32) {
#pragma unroll
    for (int i = 0; i < 2; ++i) {
      int c = t + i * 256;
      int row = c >> 2, x = c & 3;
      gload16(A + (size_t)(m0 + row) * K + kt + x * 8, (char*)As + c * 16);
      gload16(Bt + (size_t)(n0 + row) * K + kt + x * 8, (char*)Bs + c * 16);
    }
    __syncthreads();
    bf16x8 af[4], bfr[4];
#pragma unroll
    for (int m = 0; m < 4; ++m) {
      int row = wm * 64 + m * 16 + l15;
      af[m] = *(const bf16x8*)(As + row * 32 + g * 8);
    }
#pragma unroll
    for (int n = 0; n < 4; ++n) {
      int row = wn * 64 + n * 16 + l15;
      bfr[n] = *(const bf16x8*)(Bs + row * 32 + g * 8);
    }
#pragma unroll
    for (int m = 0; m < 4; ++m)
#pragma unroll
      for (int n = 0; n < 4; ++n)
        acc[m][n] = __builtin_amdgcn_mfma_f32_16x16x32_bf16(af[m], bfr[n], acc[m][n], 0, 0, 0);
    __syncthreads();
  }

  float bias_v[4];
#pragma unroll
  for (int n = 0; n < 4; ++n) bias_v[n] = bias[n0 + wn * 64 + n * 16 + l15];

#pragma unroll
  for (int m = 0; m < 4; ++m) {
#pragma unroll
    for (int n = 0; n < 4; ++n) {
      int col = n0 + wn * 64 + n * 16 + l15;
      if (EPI == 1) {
        int row_base = m0 + wm * 64 + m * 16 + g * 4;
        int bb = row_base >> 11;        // / 2048
        int key = row_base & 2047;
        int h = col >> 6, hd = col & 63;
        ushort4 pk;
        pk.x = f2bf(acc[m][n][0] + bias_v[n]);
        pk.y = f2bf(acc[m][n][1] + bias_v[n]);
        pk.z = f2bf(acc[m][n][2] + bias_v[n]);
        pk.w = f2bf(acc[m][n][3] + bias_v[n]);
        *(ushort4*)((ushort*)Cout + ((size_t)((bb * 16 + h) * 64 + hd)) * 2048 + key) = pk;
      } else {
#pragma unroll
        for (int j = 0; j < 4; ++j) {
          int row = m0 + wm * 64 + m * 16 + g * 4 + j;
          float v = acc[m][n][j] + bias_v[n];
          if (EPI == 0) {
            ((ushort*)Cout)[(size_t)row * N + col] = f2bf(v);
          } else {
            size_t idx = (size_t)row * N + col;
            ((float*)Cout)[idx] = v + residual[idx];
          }
        }
      }
    }
  }
}

// ---------------- fused flash attention ----------------
// grid: (LQ/64, B*H). 256 threads = 4 waves, each wave owns 16 q-rows.
__global__ __launch_bounds__(256) void attn_kernel(
    const ushort* __restrict__ Qb, const ushort* __restrict__ Kb,
    const ushort* __restrict__ Vt, const int* __restrict__ mask,
    ushort* __restrict__ ctx) {
  __shared__ float mbias[2048];
  __shared__ ushort Ks[64 * 64];   // [key][dim], XOR-swizzled rows
  __shared__ ushort Vs[64 * 64];   // [dim][key], XOR-swizzled rows
  __shared__ ushort Ps[4][16 * 64];// per-wave P tile [qrow][key], swizzled

  const int t = threadIdx.x, lane = t & 63, w = t >> 6;
  const int l15 = lane & 15, g = lane >> 4;
  const int b = blockIdx.y >> 4, h = blockIdx.y & 15;
  const int q0 = blockIdx.x * 64;

  for (int i = t; i < 2048; i += 256)
    mbias[i] = mask[b * 2048 + i] ? 0.0f : -1e30f;

  // Q fragments held in registers for the whole block
  bf16x8 aq[2];
  {
    int qrow = q0 + w * 16 + l15;
    const ushort* qp = Qb + ((size_t)(b * 1024 + qrow)) * 1024 + h * 64;
    aq[0] = *(const bf16x8*)(qp + g * 8);
    aq[1] = *(const bf16x8*)(qp + 32 + g * 8);
  }

  f32x4 o_acc[4] = {};
  float m_run[4], l_run[4];
#pragma unroll
  for (int j = 0; j < 4; ++j) { m_run[j] = -1e30f; l_run[j] = 0.0f; }
  const float scale = 0.125f;  // HD^-0.5

  __syncthreads();

  for (int kt = 0; kt < 2048; kt += 64) {
    // stage K tile [64 keys][64 dims] and V tile [64 dims][64 keys], source pre-swizzled
#pragma unroll
    for (int i = 0; i < 2; ++i) {
      int c = t + i * 256;
      int r = c >> 3, xp = c & 7;
      int xl = xp ^ (r & 7);
      gload16(Kb + ((size_t)(b * 2048 + kt + r)) * 1024 + h * 64 + xl * 8,
              (char*)Ks + c * 16);
      gload16(Vt + ((size_t)((b * 16 + h) * 64 + r)) * 2048 + kt + xl * 8,
              (char*)Vs + c * 16);
    }
    __syncthreads();

    // S = Q K^T  (16q x 64k per wave)
    f32x4 sacc[4] = {};
#pragma unroll
    for (int n = 0; n < 4; ++n) {
      int key = n * 16 + l15;
#pragma unroll
      for (int kc = 0; kc < 2; ++kc) {
        int kb2 = (kc * 32 + g * 8) * 2;
        bf16x8 bk = *(const bf16x8*)((char*)Ks + key * 128 + (kb2 ^ ((key & 7) << 4)));
        sacc[n] = __builtin_amdgcn_mfma_f32_16x16x32_bf16(aq[kc], bk, sacc[n], 0, 0, 0);
      }
    }

    // online softmax
    float sv[4][4], tm[4];
#pragma unroll
    for (int j = 0; j < 4; ++j) tm[j] = -1e30f;
#pragma unroll
    for (int n = 0; n < 4; ++n) {
      float mb = mbias[kt + n * 16 + l15];
#pragma unroll
      for (int j = 0; j < 4; ++j) {
        sv[n][j] = sacc[n][j] * scale + mb;
        tm[j] = fmaxf(tm[j], sv[n][j]);
      }
    }
#pragma unroll
    for (int j = 0; j < 4; ++j) {
      tm[j] = fmaxf(tm[j], __shfl_xor(tm[j], 1));
      tm[j] = fmaxf(tm[j], __shfl_xor(tm[j], 2));
      tm[j] = fmaxf(tm[j], __shfl_xor(tm[j], 4));
      tm[j] = fmaxf(tm[j], __shfl_xor(tm[j], 8));
    }
    float alpha[4], psum[4];
#pragma unroll
    for (int j = 0; j < 4; ++j) {
      float mn = fmaxf(m_run[j], tm[j]);
      alpha[j] = __expf(m_run[j] - mn);
      m_run[j] = mn;
      psum[j] = 0.0f;
    }
    ushort pb[4][4];
#pragma unroll
    for (int n = 0; n < 4; ++n)
#pragma unroll
      for (int j = 0; j < 4; ++j) {
        float p = __expf(sv[n][j] - m_run[j]);
        psum[j] += p;
        pb[n][j] = f2bf(p);
      }
#pragma unroll
    for (int j = 0; j < 4; ++j) {
      psum[j] += __shfl_xor(psum[j], 1);
      psum[j] += __shfl_xor(psum[j], 2);
      psum[j] += __shfl_xor(psum[j], 4);
      psum[j] += __shfl_xor(psum[j], 8);
      l_run[j] = l_run[j] * alpha[j] + psum[j];
    }
#pragma unroll
    for (int df = 0; df < 4; ++df)
#pragma unroll
      for (int j = 0; j < 4; ++j) o_acc[df][j] *= alpha[j];

    // P -> LDS (per-wave private, swizzled [16][64])
    char* pw = (char*)Ps[w];
#pragma unroll
    for (int n = 0; n < 4; ++n)
#pragma unroll
      for (int j = 0; j < 4; ++j) {
        int r = g * 4 + j;
        int key = n * 16 + l15;
        *(ushort*)(pw + r * 128 + ((key * 2) ^ ((r & 7) << 4))) = pb[n][j];
      }

    // O += P V
#pragma unroll
    for (int kc = 0; kc < 2; ++kc) {
      int kb2 = (kc * 32 + g * 8) * 2;
      bf16x8 pa = *(const bf16x8*)(pw + l15 * 128 + (kb2 ^ ((l15 & 7) << 4)));
#pragma unroll
      for (int df = 0; df < 4; ++df) {
        int d = df * 16 + l15;
        bf16x8 bv = *(const bf16x8*)((char*)Vs + d * 128 + (kb2 ^ ((d & 7) << 4)));
        o_acc[df] = __builtin_amdgcn_mfma_f32_16x16x32_bf16(pa, bv, o_acc[df], 0, 0, 0);
      }
    }
    __syncthreads();
  }

  // finalize: divide by l, write ctx bf16 [B][LQ][D]
#pragma unroll
  for (int j = 0; j < 4; ++j) l_run[j] = 1.0f / l_run[j];
  int qrow_base = q0 + w * 16 + g * 4;
#pragma unroll
  for (int df = 0; df < 4; ++df) {
    int col = h * 64 + df * 16 + l15;
#pragma unroll
    for (int j = 0; j < 4; ++j) {
      int qrow = qrow_base + j;
      ctx[((size_t)(b * 1024 + qrow)) * 1024 + col] = f2bf(o_acc[df][j] * l_run[j]);
    }
  }
}

extern "C" void kernel_launch(void* const* d_in, const int* in_sizes, int n_in,
                              void* d_out, int out_size, void* d_ws, size_t ws_size,
                              hipStream_t stream) {
  const float* query = (const float*)d_in[0];
  const float* key   = (const float*)d_in[1];
  const float* value = (const float*)d_in[2];
  const int*   mask  = (const int*)d_in[3];
  const float* Wq = (const float*)d_in[4];
  const float* bq = (const float*)d_in[5];
  const float* Wk = (const float*)d_in[6];
  const float* bk = (const float*)d_in[7];
  const float* Wv = (const float*)d_in[8];
  const float* bv = (const float*)d_in[9];
  const float* Wo = (const float*)d_in[10];
  const float* bo = (const float*)d_in[11];
  const float* ln_g = (const float*)d_in[12];
  const float* ln_b = (const float*)d_in[13];
  float* out = (float*)d_out;

  char* p = (char*)d_ws;
  auto alloc = [&](size_t elems) { ushort* r = (ushort*)p; p += elems * 2; return r; };
  ushort* WqT  = alloc((size_t)1024 * 1024);
  ushort* WkT  = alloc((size_t)1024 * 512);
  ushort* WvT  = alloc((size_t)1024 * 512);
  ushort* WoT  = alloc((size_t)1024 * 1024);
  ushort* qn   = alloc((size_t)4096 * 1024);
  ushort* keyb = alloc((size_t)8192 * 512);
  ushort* valb = alloc((size_t)8192 * 512);
  ushort* Qb   = alloc((size_t)4096 * 1024);
  ushort* Kb   = alloc((size_t)8192 * 1024);
  ushort* Vt   = alloc((size_t)8192 * 1024);
  ushort* ctx  = alloc((size_t)4096 * 1024);
  (void)ws_size; (void)in_sizes; (void)n_in; (void)out_size;

  dim3 blk(256);
  transpose_cast_kernel<<<dim3(16, 16), blk, 0, stream>>>(Wq, WqT, 1024, 1024);
  transpose_cast_kernel<<<dim3(8, 16),  blk, 0, stream>>>(Wk, WkT, 512, 1024);
  transpose_cast_kernel<<<dim3(8, 16),  blk, 0, stream>>>(Wv, WvT, 512, 1024);
  transpose_cast_kernel<<<dim3(16, 16), blk, 0, stream>>>(Wo, WoT, 1024, 1024);
  cast_bf16_kernel<<<dim3(1024), blk, 0, stream>>>((const float4*)key,   (ushort4*)keyb, (8192 * 512) / 4);
  cast_bf16_kernel<<<dim3(1024), blk, 0, stream>>>((const float4*)value, (ushort4*)valb, (8192 * 512) / 4);
  ln_kernel<<<dim3(4096), blk, 0, stream>>>(query, ln_g, ln_b, qn);

  gemm_bt_kernel<0><<<dim3(8, 32), blk, 0, stream>>>(qn,   WqT, bq, Qb, nullptr, 4096, 1024, 1024);
  gemm_bt_kernel<0><<<dim3(8, 64), blk, 0, stream>>>(keyb, WkT, bk, Kb, nullptr, 8192, 1024, 512);
  gemm_bt_kernel<1><<<dim3(8, 64), blk, 0, stream>>>(valb, WvT, bv, Vt, nullptr, 8192, 1024, 512);

  attn_kernel<<<dim3(16, 64), blk, 0, stream>>>(Qb, Kb, Vt, mask, ctx);

  gemm_bt_kernel<2><<<dim3(8, 32), blk, 0, stream>>>(ctx, WoT, bo, out, query, 4096, 1024, 1024);
}

// Round 2
// 224.498 us; speedup vs baseline: 1.0741x; 1.0741x over previous
//
#include <hip/hip_runtime.h>
#include <hip/hip_bf16.h>
#include <stdint.h>

// Problem constants
#define Bn 4
#define LQ 1024
#define LK 2048
#define Dm 1024
#define Hn 16
#define HD 64

typedef __attribute__((ext_vector_type(4))) float f32x4;
typedef __attribute__((ext_vector_type(8))) short bf16x8;

__device__ __forceinline__ ushort f2bf(float f) {
  union { float f; uint32_t u; } v; v.f = f;
  uint32_t r = v.u + 0x7FFF + ((v.u >> 16) & 1);
  return (ushort)(r >> 16);
}

__device__ __forceinline__ uint32_t cvt_pk_bf16(float lo, float hi) {
  uint32_t r;
  asm volatile("v_cvt_pk_bf16_f32 %0, %1, %2" : "=v"(r) : "v"(lo), "v"(hi));
  return r;
}

__device__ __forceinline__ void gload16(const void* g, void* lds) {
  __builtin_amdgcn_global_load_lds(
      (const __attribute__((address_space(1))) void*)g,
      (__attribute__((address_space(3))) void*)lds, 16, 0, 0);
}

__device__ __forceinline__ void wait_vm0_barrier() {
  asm volatile("s_waitcnt vmcnt(0)" ::: "memory");
  __builtin_amdgcn_s_barrier();
}

// ---------------- weight transpose + cast: W[K][N] f32 -> Wt[N][K] bf16 ----------------
__global__ __launch_bounds__(256) void transpose_cast_kernel(
    const float* __restrict__ W, ushort* __restrict__ Wt, int K, int N) {
  __shared__ float tile[64][65];
  int k0 = blockIdx.x * 64, n0 = blockIdx.y * 64;
  int tx = threadIdx.x & 63, ty = threadIdx.x >> 6;
#pragma unroll
  for (int i = 0; i < 16; ++i) {
    int r = ty + i * 4;
    tile[r][tx] = W[(size_t)(k0 + r) * N + n0 + tx];
  }
  __syncthreads();
#pragma unroll
  for (int i = 0; i < 16; ++i) {
    int r = ty + i * 4;
    Wt[(size_t)(n0 + r) * K + k0 + tx] = f2bf(tile[tx][r]);
  }
}

// ---------------- elementwise f32 -> bf16 cast ----------------
__global__ __launch_bounds__(256) void cast_bf16_kernel(
    const float4* __restrict__ in, ushort4* __restrict__ out, int n4) {
  int i = blockIdx.x * blockDim.x + threadIdx.x;
  int stride = gridDim.x * blockDim.x;
  for (; i < n4; i += stride) {
    float4 v = in[i];
    out[i] = make_ushort4(f2bf(v.x), f2bf(v.y), f2bf(v.z), f2bf(v.w));
  }
}

// ---------------- LayerNorm over D=1024, f32 in -> bf16 out ----------------
__global__ __launch_bounds__(256) void ln_kernel(
    const float* __restrict__ x, const float* __restrict__ g,
    const float* __restrict__ b, ushort* __restrict__ y) {
  int row = blockIdx.x;
  const float4* xr = (const float4*)(x + (size_t)row * 1024);
  float4 v = xr[threadIdx.x];
  float s1 = v.x + v.y + v.z + v.w;
  float s2 = v.x * v.x + v.y * v.y + v.z * v.z + v.w * v.w;
#pragma unroll
  for (int off = 32; off > 0; off >>= 1) {
    s1 += __shfl_down(s1, off);
    s2 += __shfl_down(s2, off);
  }
  __shared__ float r1[4], r2[4];
  int w = threadIdx.x >> 6, lane = threadIdx.x & 63;
  if (lane == 0) { r1[w] = s1; r2[w] = s2; }
  __syncthreads();
  s1 = r1[0] + r1[1] + r1[2] + r1[3];
  s2 = r2[0] + r2[1] + r2[2] + r2[3];
  float mu = s1 * (1.0f / 1024.0f);
  float var = s2 * (1.0f / 1024.0f) - mu * mu;
  float rstd = rsqrtf(var + 1e-5f);
  float4 gv = ((const float4*)g)[threadIdx.x];
  float4 bv = ((const float4*)b)[threadIdx.x];
  ushort4 o;
  o.x = f2bf((v.x - mu) * rstd * gv.x + bv.x);
  o.y = f2bf((v.y - mu) * rstd * gv.y + bv.y);
  o.z = f2bf((v.z - mu) * rstd * gv.z + bv.z);
  o.w = f2bf((v.w - mu) * rstd * gv.w + bv.w);
  ((ushort4*)(y + (size_t)row * 1024))[threadIdx.x] = o;
}

// ---------------- GEMM: C[M][N] = A[M][K](bf16) @ Bt[N][K]^T(bf16) + bias ----------------
// 2-phase pipelined: stage tile t+1 before computing tile t; vmcnt(0)+barrier at end.
// EPI 0: bf16 row-major out.  EPI 1: bf16 out scattered to Vt[(b*16+h)*64+hd][LK].
// EPI 2: f32 out + residual.
template <int EPI>
__global__ __launch_bounds__(256) void gemm_bt_kernel(
    const ushort* __restrict__ A, const ushort* __restrict__ Bt,
    const float* __restrict__ bias, void* __restrict__ Cout,
    const float* __restrict__ residual, int M, int N, int K) {
  __shared__ ushort As[2][128 * 32];
  __shared__ ushort Bs[2][128 * 32];
  const int t = threadIdx.x;
  const int lane = t & 63;
  const int w = t >> 6;
  const int wm = w >> 1, wn = w & 1;
  const int m0 = blockIdx.y * 128, n0 = blockIdx.x * 128;
  const int l15 = lane & 15, g = lane >> 4;

  f32x4 acc[4][4] = {};

  auto stage = [&](int buf, int kt) {
#pragma unroll
    for (int i = 0; i < 2; ++i) {
      int c = t + i * 256;
      int row = c >> 2, x = c & 3;
      gload16(A + (size_t)(m0 + row) * K + kt + x * 8, (char*)As[buf] + c * 16);
      gload16(Bt + (size_t)(n0 + row) * K + kt + x * 8, (char*)Bs[buf] + c * 16);
    }
  };

  stage(0, 0);
  wait_vm0_barrier();

  int cur = 0;
  for (int kt = 0; kt < K; kt += 32) {
    if (kt + 32 < K) stage(cur ^ 1, kt + 32);
    bf16x8 af[4], bfr[4];
#pragma unroll
    for (int m = 0; m < 4; ++m) {
      int row = wm * 64 + m * 16 + l15;
      af[m] = *(const bf16x8*)(As[cur] + row * 32 + g * 8);
    }
#pragma unroll
    for (int n = 0; n < 4; ++n) {
      int row = wn * 64 + n * 16 + l15;
      bfr[n] = *(const bf16x8*)(Bs[cur] + row * 32 + g * 8);
    }
#pragma unroll
    for (int m = 0; m < 4; ++m)
#pragma unroll
      for (int n = 0; n < 4; ++n)
        acc[m][n] = __builtin_amdgcn_mfma_f32_16x16x32_bf16(af[m], bfr[n], acc[m][n], 0, 0, 0);
    wait_vm0_barrier();
    cur ^= 1;
  }

  float bias_v[4];
#pragma unroll
  for (int n = 0; n < 4; ++n) bias_v[n] = bias[n0 + wn * 64 + n * 16 + l15];

#pragma unroll
  for (int m = 0; m < 4; ++m) {
#pragma unroll
    for (int n = 0; n < 4; ++n) {
      int col = n0 + wn * 64 + n * 16 + l15;
      if (EPI == 1) {
        int row_base = m0 + wm * 64 + m * 16 + g * 4;
        int bb = row_base >> 11;        // / 2048
        int key = row_base & 2047;
        int h = col >> 6, hd = col & 63;
        ushort4 pk;
        pk.x = f2bf(acc[m][n][0] + bias_v[n]);
        pk.y = f2bf(acc[m][n][1] + bias_v[n]);
        pk.z = f2bf(acc[m][n][2] + bias_v[n]);
        pk.w = f2bf(acc[m][n][3] + bias_v[n]);
        *(ushort4*)((ushort*)Cout + ((size_t)((bb * 16 + h) * 64 + hd)) * 2048 + key) = pk;
      } else {
#pragma unroll
        for (int j = 0; j < 4; ++j) {
          int row = m0 + wm * 64 + m * 16 + g * 4 + j;
          float v = acc[m][n][j] + bias_v[n];
          if (EPI == 0) {
            ((ushort*)Cout)[(size_t)row * N + col] = f2bf(v);
          } else {
            size_t idx = (size_t)row * N + col;
            ((float*)Cout)[idx] = v + residual[idx];
          }
        }
      }
    }
  }
}

// ---------------- fused flash attention ----------------
// grid: (LQ/64, B*H) with XCD-chunked swizzle. 256 threads = 4 waves, 16 q-rows/wave.
// 2-phase pipelined K/V staging, defer-max online softmax, cvt_pk P-pack.
__global__ __launch_bounds__(256) void attn_kernel(
    const ushort* __restrict__ Qb, const ushort* __restrict__ Kb,
    const ushort* __restrict__ Vt, const int* __restrict__ mask,
    ushort* __restrict__ ctx) {
  __shared__ ushort Ks[2][64 * 64];   // [key][dim], XOR-swizzled rows, dbuf
  __shared__ ushort Vs[2][64 * 64];   // [dim][key], XOR-swizzled rows, dbuf
  __shared__ ushort Ps[4][16 * 64];   // per-wave P tile [qrow][key], swizzled

  const int t = threadIdx.x, lane = t & 63, w = t >> 6;
  const int l15 = lane & 15, g = lane >> 4;
  // XCD-chunked swizzle: 1024 blocks, 8 XCDs, chunk=128 -> each XCD owns 8 (b,h) groups
  int o = blockIdx.y * gridDim.x + blockIdx.x;
  int logical = (o & 7) * 128 + (o >> 3);
  const int b = logical >> 8;
  const int h = (logical >> 4) & 15;
  const int q0 = (logical & 15) * 64;
  const int* maskp = mask + b * 2048;

  // Q fragments held in registers for the whole block
  bf16x8 aq[2];
  {
    int qrow = q0 + w * 16 + l15;
    const ushort* qp = Qb + ((size_t)(b * 1024 + qrow)) * 1024 + h * 64;
    aq[0] = *(const bf16x8*)(qp + g * 8);
    aq[1] = *(const bf16x8*)(qp + 32 + g * 8);
  }

  f32x4 o_acc[4] = {};
  float m_run[4], l_run[4];
#pragma unroll
  for (int j = 0; j < 4; ++j) { m_run[j] = -1e30f; l_run[j] = 0.0f; }
  const float scale = 0.125f;  // HD^-0.5

  auto stageKV = [&](int buf, int kt) {
#pragma unroll
    for (int i = 0; i < 2; ++i) {
      int c = t + i * 256;
      int r = c >> 3, xp = c & 7;
      int xl = xp ^ (r & 7);
      gload16(Kb + ((size_t)(b * 2048 + kt + r)) * 1024 + h * 64 + xl * 8,
              (char*)Ks[buf] + c * 16);
      gload16(Vt + ((size_t)((b * 16 + h) * 64 + r)) * 2048 + kt + xl * 8,
              (char*)Vs[buf] + c * 16);
    }
  };

  stageKV(0, 0);
  wait_vm0_barrier();

  int cur = 0;
  for (int kt = 0; kt < 2048; kt += 64) {
    if (kt + 64 < 2048) stageKV(cur ^ 1, kt + 64);

    float mb[4];
#pragma unroll
    for (int n = 0; n < 4; ++n) mb[n] = maskp[kt + n * 16 + l15] ? 0.0f : -1e30f;

    // S = Q K^T  (16q x 64k per wave)
    f32x4 sacc[4] = {};
    __builtin_amdgcn_s_setprio(1);
#pragma unroll
    for (int n = 0; n < 4; ++n) {
      int key = n * 16 + l15;
#pragma unroll
      for (int kc = 0; kc < 2; ++kc) {
        int kb2 = (kc * 32 + g * 8) * 2;
        bf16x8 bk = *(const bf16x8*)((char*)Ks[cur] + key * 128 + (kb2 ^ ((key & 7) << 4)));
        sacc[n] = __builtin_amdgcn_mfma_f32_16x16x32_bf16(aq[kc], bk, sacc[n], 0, 0, 0);
      }
    }
    __builtin_amdgcn_s_setprio(0);

    // online softmax (defer-max, THR=8)
    float sv[4][4], tm[4];
#pragma unroll
    for (int j = 0; j < 4; ++j) tm[j] = -1e30f;
#pragma unroll
    for (int n = 0; n < 4; ++n) {
#pragma unroll
      for (int j = 0; j < 4; ++j) {
        sv[n][j] = sacc[n][j] * scale + mb[n];
        tm[j] = fmaxf(tm[j], sv[n][j]);
      }
    }
#pragma unroll
    for (int j = 0; j < 4; ++j) {
      tm[j] = fmaxf(tm[j], __shfl_xor(tm[j], 1));
      tm[j] = fmaxf(tm[j], __shfl_xor(tm[j], 2));
      tm[j] = fmaxf(tm[j], __shfl_xor(tm[j], 4));
      tm[j] = fmaxf(tm[j], __shfl_xor(tm[j], 8));
    }
    float growth = fmaxf(fmaxf(tm[0] - m_run[0], tm[1] - m_run[1]),
                         fmaxf(tm[2] - m_run[2], tm[3] - m_run[3]));
    if (__any(growth > 8.0f)) {
#pragma unroll
      for (int j = 0; j < 4; ++j) {
        float mn = fmaxf(m_run[j], tm[j]);
        float alpha = __expf(m_run[j] - mn);
        m_run[j] = mn;
        l_run[j] *= alpha;
#pragma unroll
        for (int df = 0; df < 4; ++df) o_acc[df][j] *= alpha;
      }
    }
    float psum[4] = {0.0f, 0.0f, 0.0f, 0.0f};
    uint32_t pk[4][2];
#pragma unroll
    for (int n = 0; n < 4; ++n) {
      float p[4];
#pragma unroll
      for (int j = 0; j < 4; ++j) {
        p[j] = __expf(sv[n][j] - m_run[j]);
        psum[j] += p[j];
      }
      pk[n][0] = cvt_pk_bf16(p[0], p[1]);
      pk[n][1] = cvt_pk_bf16(p[2], p[3]);
    }
#pragma unroll
    for (int j = 0; j < 4; ++j) {
      psum[j] += __shfl_xor(psum[j], 1);
      psum[j] += __shfl_xor(psum[j], 2);
      psum[j] += __shfl_xor(psum[j], 4);
      psum[j] += __shfl_xor(psum[j], 8);
      l_run[j] += psum[j];
    }

    // P -> LDS (per-wave private, swizzled [16][64])
    char* pw = (char*)Ps[w];
#pragma unroll
    for (int n = 0; n < 4; ++n) {
      int key2 = (n * 16 + l15) * 2;
#pragma unroll
      for (int j = 0; j < 4; ++j) {
        int r = g * 4 + j;
        *(ushort*)(pw + r * 128 + (key2 ^ ((r & 7) << 4))) =
            (ushort)(pk[n][j >> 1] >> ((j & 1) * 16));
      }
    }

    // O += P V
    __builtin_amdgcn_s_setprio(1);
#pragma unroll
    for (int kc = 0; kc < 2; ++kc) {
      int kb2 = (kc * 32 + g * 8) * 2;
      bf16x8 pa = *(const bf16x8*)(pw + l15 * 128 + (kb2 ^ ((l15 & 7) << 4)));
#pragma unroll
      for (int df = 0; df < 4; ++df) {
        int d = df * 16 + l15;
        bf16x8 bv = *(const bf16x8*)((char*)Vs[cur] + d * 128 + (kb2 ^ ((d & 7) << 4)));
        o_acc[df] = __builtin_amdgcn_mfma_f32_16x16x32_bf16(pa, bv, o_acc[df], 0, 0, 0);
      }
    }
    __builtin_amdgcn_s_setprio(0);

    wait_vm0_barrier();
    cur ^= 1;
  }

  // finalize: divide by l, write ctx bf16 [B][LQ][D]
#pragma unroll
  for (int j = 0; j < 4; ++j) l_run[j] = 1.0f / l_run[j];
  int qrow_base = q0 + w * 16 + g * 4;
#pragma unroll
  for (int df = 0; df < 4; ++df) {
    int col = h * 64 + df * 16 + l15;
#pragma unroll
    for (int j = 0; j < 4; ++j) {
      int qrow = qrow_base + j;
      ctx[((size_t)(b * 1024 + qrow)) * 1024 + col] = f2bf(o_acc[df][j] * l_run[j]);
    }
  }
}

extern "C" void kernel_launch(void* const* d_in, const int* in_sizes, int n_in,
                              void* d_out, int out_size, void* d_ws, size_t ws_size,
                              hipStream_t stream) {
  const float* query = (const float*)d_in[0];
  const float* key   = (const float*)d_in[1];
  const float* value = (const float*)d_in[2];
  const int*   mask  = (const int*)d_in[3];
  const float* Wq = (const float*)d_in[4];
  const float* bq = (const float*)d_in[5];
  const float* Wk = (const float*)d_in[6];
  const float* bk = (const float*)d_in[7];
  const float* Wv = (const float*)d_in[8];
  const float* bv = (const float*)d_in[9];
  const float* Wo = (const float*)d_in[10];
  const float* bo = (const float*)d_in[11];
  const float* ln_g = (const float*)d_in[12];
  const float* ln_b = (const float*)d_in[13];
  float* out = (float*)d_out;

  char* p = (char*)d_ws;
  auto alloc = [&](size_t elems) { ushort* r = (ushort*)p; p += elems * 2; return r; };
  ushort* WqT  = alloc((size_t)1024 * 1024);
  ushort* WkT  = alloc((size_t)1024 * 512);
  ushort* WvT  = alloc((size_t)1024 * 512);
  ushort* WoT  = alloc((size_t)1024 * 1024);
  ushort* qn   = alloc((size_t)4096 * 1024);
  ushort* keyb = alloc((size_t)8192 * 512);
  ushort* valb = alloc((size_t)8192 * 512);
  ushort* Qb   = alloc((size_t)4096 * 1024);
  ushort* Kb   = alloc((size_t)8192 * 1024);
  ushort* Vt   = alloc((size_t)8192 * 1024);
  ushort* ctx  = alloc((size_t)4096 * 1024);
  (void)ws_size; (void)in_sizes; (void)n_in; (void)out_size;

  dim3 blk(256);
  transpose_cast_kernel<<<dim3(16, 16), blk, 0, stream>>>(Wq, WqT, 1024, 1024);
  transpose_cast_kernel<<<dim3(8, 16),  blk, 0, stream>>>(Wk, WkT, 512, 1024);
  transpose_cast_kernel<<<dim3(8, 16),  blk, 0, stream>>>(Wv, WvT, 512, 1024);
  transpose_cast_kernel<<<dim3(16, 16), blk, 0, stream>>>(Wo, WoT, 1024, 1024);
  cast_bf16_kernel<<<dim3(1024), blk, 0, stream>>>((const float4*)key,   (ushort4*)keyb, (8192 * 512) / 4);
  cast_bf16_kernel<<<dim3(1024), blk, 0, stream>>>((const float4*)value, (ushort4*)valb, (8192 * 512) / 4);
  ln_kernel<<<dim3(4096), blk, 0, stream>>>(query, ln_g, ln_b, qn);

  gemm_bt_kernel<0><<<dim3(8, 32), blk, 0, stream>>>(qn,   WqT, bq, Qb, nullptr, 4096, 1024, 1024);
  gemm_bt_kernel<0><<<dim3(8, 64), blk, 0, stream>>>(keyb, WkT, bk, Kb, nullptr, 8192, 1024, 512);
  gemm_bt_kernel<1><<<dim3(8, 64), blk, 0, stream>>>(valb, WvT, bv, Vt, nullptr, 8192, 1024, 512);

  attn_kernel<<<dim3(16, 64), blk, 0, stream>>>(Qb, Kb, Vt, mask, ctx);

  gemm_bt_kernel<2><<<dim3(8, 32), blk, 0, stream>>>(ctx, WoT, bo, out, query, 4096, 1024, 1024);
}

// Round 3
// 208.126 us; speedup vs baseline: 1.1586x; 1.0787x over previous
//
#include <hip/hip_runtime.h>
#include <hip/hip_bf16.h>
#include <stdint.h>

// Problem constants
#define Bn 4
#define LQ 1024
#define LK 2048
#define Dm 1024
#define Hn 16
#define HD 64

typedef __attribute__((ext_vector_type(4))) float f32x4;
typedef __attribute__((ext_vector_type(8))) short bf16x8;
typedef __attribute__((ext_vector_type(2))) uint32_t u32x2;

__device__ __forceinline__ ushort f2bf(float f) {
  union { float f; uint32_t u; } v; v.f = f;
  uint32_t r = v.u + 0x7FFF + ((v.u >> 16) & 1);
  return (ushort)(r >> 16);
}

__device__ __forceinline__ uint32_t cvt_pk_bf16(float lo, float hi) {
  uint32_t r;
  asm("v_cvt_pk_bf16_f32 %0, %1, %2" : "=v"(r) : "v"(lo), "v"(hi));
  return r;
}

__device__ __forceinline__ float exp2v(float x) {  // D = 2^x
  float r;
  asm("v_exp_f32 %0, %1" : "=v"(r) : "v"(x));
  return r;
}

__device__ __forceinline__ void gload16(const void* g, void* lds) {
  __builtin_amdgcn_global_load_lds(
      (const __attribute__((address_space(1))) void*)g,
      (__attribute__((address_space(3))) void*)lds, 16, 0, 0);
}

__device__ __forceinline__ void wait_vm0_barrier() {
  asm volatile("s_waitcnt vmcnt(0)" ::: "memory");
  __builtin_amdgcn_s_barrier();
}

// ---------------- weight transpose + cast: W[K][N] f32 -> Wt[N][K] bf16 ----------------
__global__ __launch_bounds__(256) void transpose_cast_kernel(
    const float* __restrict__ W, ushort* __restrict__ Wt, int K, int N) {
  __shared__ float tile[64][65];
  int k0 = blockIdx.x * 64, n0 = blockIdx.y * 64;
  int tx = threadIdx.x & 63, ty = threadIdx.x >> 6;
#pragma unroll
  for (int i = 0; i < 16; ++i) {
    int r = ty + i * 4;
    tile[r][tx] = W[(size_t)(k0 + r) * N + n0 + tx];
  }
  __syncthreads();
#pragma unroll
  for (int i = 0; i < 16; ++i) {
    int r = ty + i * 4;
    Wt[(size_t)(n0 + r) * K + k0 + tx] = f2bf(tile[tx][r]);
  }
}

// ---------------- elementwise f32 -> bf16 cast ----------------
__global__ __launch_bounds__(256) void cast_bf16_kernel(
    const float4* __restrict__ in, ushort4* __restrict__ out, int n4) {
  int i = blockIdx.x * blockDim.x + threadIdx.x;
  int stride = gridDim.x * blockDim.x;
  for (; i < n4; i += stride) {
    float4 v = in[i];
    out[i] = make_ushort4(f2bf(v.x), f2bf(v.y), f2bf(v.z), f2bf(v.w));
  }
}

// ---------------- LayerNorm over D=1024, f32 in -> bf16 out ----------------
__global__ __launch_bounds__(256) void ln_kernel(
    const float* __restrict__ x, const float* __restrict__ g,
    const float* __restrict__ b, ushort* __restrict__ y) {
  int row = blockIdx.x;
  const float4* xr = (const float4*)(x + (size_t)row * 1024);
  float4 v = xr[threadIdx.x];
  float s1 = v.x + v.y + v.z + v.w;
  float s2 = v.x * v.x + v.y * v.y + v.z * v.z + v.w * v.w;
#pragma unroll
  for (int off = 32; off > 0; off >>= 1) {
    s1 += __shfl_down(s1, off);
    s2 += __shfl_down(s2, off);
  }
  __shared__ float r1[4], r2[4];
  int w = threadIdx.x >> 6, lane = threadIdx.x & 63;
  if (lane == 0) { r1[w] = s1; r2[w] = s2; }
  __syncthreads();
  s1 = r1[0] + r1[1] + r1[2] + r1[3];
  s2 = r2[0] + r2[1] + r2[2] + r2[3];
  float mu = s1 * (1.0f / 1024.0f);
  float var = s2 * (1.0f / 1024.0f) - mu * mu;
  float rstd = rsqrtf(var + 1e-5f);
  float4 gv = ((const float4*)g)[threadIdx.x];
  float4 bv = ((const float4*)b)[threadIdx.x];
  ushort4 o;
  o.x = f2bf((v.x - mu) * rstd * gv.x + bv.x);
  o.y = f2bf((v.y - mu) * rstd * gv.y + bv.y);
  o.z = f2bf((v.z - mu) * rstd * gv.z + bv.z);
  o.w = f2bf((v.w - mu) * rstd * gv.w + bv.w);
  ((ushort4*)(y + (size_t)row * 1024))[threadIdx.x] = o;
}

// ---------------- GEMM: C[M][N] = A[M][K](bf16) @ Bt[N][K]^T(bf16) + bias ----------------
// 2-phase pipelined, pointer-hoisted staging.
// EPI 0: bf16 out, value (acc+bias)*osc.  EPI 1: bf16 out scattered to Vt.  EPI 2: f32 + residual.
template <int EPI>
__global__ __launch_bounds__(256) void gemm_bt_kernel(
    const ushort* __restrict__ A, const ushort* __restrict__ Bt,
    const float* __restrict__ bias, void* __restrict__ Cout,
    const float* __restrict__ residual, int M, int N, int K, float osc) {
  __shared__ ushort As[2][128 * 32];
  __shared__ ushort Bs[2][128 * 32];
  const int t = threadIdx.x;
  const int lane = t & 63;
  const int w = t >> 6;
  const int wm = w >> 1, wn = w & 1;
  const int m0 = blockIdx.y * 128, n0 = blockIdx.x * 128;
  const int l15 = lane & 15, g = lane >> 4;

  f32x4 acc[4][4] = {};

  const int c0 = t, c1 = t + 256;
  const int arow0 = c0 >> 2, ax0 = (c0 & 3) * 8;
  const int arow1 = c1 >> 2, ax1 = (c1 & 3) * 8;
  const ushort* Ap0 = A + (size_t)(m0 + arow0) * K + ax0;
  const ushort* Ap1 = A + (size_t)(m0 + arow1) * K + ax1;
  const ushort* Bp0 = Bt + (size_t)(n0 + arow0) * K + ax0;
  const ushort* Bp1 = Bt + (size_t)(n0 + arow1) * K + ax1;

  auto stage = [&](int buf, int kt) {
    gload16(Ap0 + kt, (char*)As[buf] + c0 * 16);
    gload16(Ap1 + kt, (char*)As[buf] + c1 * 16);
    gload16(Bp0 + kt, (char*)Bs[buf] + c0 * 16);
    gload16(Bp1 + kt, (char*)Bs[buf] + c1 * 16);
  };

  stage(0, 0);
  wait_vm0_barrier();

  int cur = 0;
  for (int kt = 0; kt < K; kt += 32) {
    if (kt + 32 < K) stage(cur ^ 1, kt + 32);
    bf16x8 af[4], bfr[4];
#pragma unroll
    for (int m = 0; m < 4; ++m) {
      int row = wm * 64 + m * 16 + l15;
      af[m] = *(const bf16x8*)(As[cur] + row * 32 + g * 8);
    }
#pragma unroll
    for (int n = 0; n < 4; ++n) {
      int row = wn * 64 + n * 16 + l15;
      bfr[n] = *(const bf16x8*)(Bs[cur] + row * 32 + g * 8);
    }
#pragma unroll
    for (int m = 0; m < 4; ++m)
#pragma unroll
      for (int n = 0; n < 4; ++n)
        acc[m][n] = __builtin_amdgcn_mfma_f32_16x16x32_bf16(af[m], bfr[n], acc[m][n], 0, 0, 0);
    wait_vm0_barrier();
    cur ^= 1;
  }

  float bias_v[4];
#pragma unroll
  for (int n = 0; n < 4; ++n) bias_v[n] = bias[n0 + wn * 64 + n * 16 + l15];

#pragma unroll
  for (int m = 0; m < 4; ++m) {
#pragma unroll
    for (int n = 0; n < 4; ++n) {
      int col = n0 + wn * 64 + n * 16 + l15;
      if (EPI == 1) {
        int row_base = m0 + wm * 64 + m * 16 + g * 4;
        int bb = row_base >> 11;        // / 2048
        int key = row_base & 2047;
        int h = col >> 6, hd = col & 63;
        ushort4 pk;
        pk.x = f2bf(acc[m][n][0] + bias_v[n]);
        pk.y = f2bf(acc[m][n][1] + bias_v[n]);
        pk.z = f2bf(acc[m][n][2] + bias_v[n]);
        pk.w = f2bf(acc[m][n][3] + bias_v[n]);
        *(ushort4*)((ushort*)Cout + ((size_t)((bb * 16 + h) * 64 + hd)) * 2048 + key) = pk;
      } else {
#pragma unroll
        for (int j = 0; j < 4; ++j) {
          int row = m0 + wm * 64 + m * 16 + g * 4 + j;
          if (EPI == 0) {
            float v = (acc[m][n][j] + bias_v[n]) * osc;
            ((ushort*)Cout)[(size_t)row * N + col] = f2bf(v);
          } else {
            size_t idx = (size_t)row * N + col;
            ((float*)Cout)[idx] = acc[m][n][j] + bias_v[n] + residual[idx];
          }
        }
      }
    }
  }
}

// ---------------- fused flash attention (swapped QK^T) ----------------
// grid: 1024 blocks, XCD-chunked. 256 threads = 4 waves, 16 q-rows/wave.
// S^T = mfma(K,Q): lane holds full P-row (16 keys) for q = lane&15 -> lane-local softmax.
// Q pre-scaled by 0.125*log2e in projection; exp via raw v_exp_f32 (base-2).
__global__ __launch_bounds__(256) void attn_kernel(
    const ushort* __restrict__ Qb, const ushort* __restrict__ Kb,
    const ushort* __restrict__ Vt, const int* __restrict__ mask,
    ushort* __restrict__ ctx) {
  __shared__ float mbias[2048];       // 8 KB
  __shared__ ushort Ks[2][64 * 64];   // [key][dim], XOR-swizzled rows, dbuf
  __shared__ ushort Vs[2][64 * 64];   // [dim][key], XOR-swizzled rows, dbuf
  __shared__ ushort Ps[4][16 * 64];   // per-wave P tile [qrow][key], swizzled

  const int t = threadIdx.x, lane = t & 63, w = t >> 6;
  const int l15 = lane & 15, g = lane >> 4, g4 = g * 4;
  // XCD-chunked swizzle: 1024 blocks, 8 XCDs, chunk=128
  int o = blockIdx.y * gridDim.x + blockIdx.x;
  int logical = (o & 7) * 128 + (o >> 3);
  const int b = logical >> 8;
  const int h = (logical >> 4) & 15;
  const int q0 = (logical & 15) * 64;
  const int* maskp = mask + b * 2048;

  // staging pointers (hoisted; advance per tile)
  const int cA = t, cB = t + 256;
  const int rA = cA >> 3, rB = cB >> 3;
  const int xA = ((cA & 7) ^ (rA & 7)) * 8, xB = ((cB & 7) ^ (rB & 7)) * 8;
  const ushort* kp = Kb + ((size_t)(b * 2048)) * 1024 + h * 64;
  const ushort* vp = Vt + ((size_t)((b * 16 + h) * 64)) * 2048;
  const size_t koffA = (size_t)rA * 1024 + xA, koffB = (size_t)rB * 1024 + xB;
  const size_t voffA = (size_t)rA * 2048 + xA, voffB = (size_t)rB * 2048 + xB;

  auto stageKV = [&](int buf) {
    char* kd = (char*)Ks[buf];
    char* vd = (char*)Vs[buf];
    gload16(kp + koffA, kd + cA * 16);
    gload16(kp + koffB, kd + cB * 16);
    gload16(vp + voffA, vd + cA * 16);
    gload16(vp + voffB, vd + cB * 16);
  };

  stageKV(0);
  for (int i = t; i < 2048; i += 256) mbias[i] = maskp[i] ? 0.0f : -1e30f;

  // Q fragments (pre-scaled by 0.125*log2e at projection time)
  bf16x8 aq[2];
  {
    int qrow = q0 + w * 16 + l15;
    const ushort* qp = Qb + ((size_t)(b * 1024 + qrow)) * 1024 + h * 64;
    aq[0] = *(const bf16x8*)(qp + g * 8);
    aq[1] = *(const bf16x8*)(qp + 32 + g * 8);
  }

  f32x4 o_acc[4] = {};
  float m_run = -1e30f, l_run = 0.0f;

  __syncthreads();  // covers staged tile 0 + mbias fill

  char* pw = (char*)Ps[w];
  const int swz = (l15 & 7) << 4;

  int cur = 0;
  for (int kt = 0; kt < 2048; kt += 64) {
    kp += 64 * 1024;
    vp += 64;
    if (kt + 64 < 2048) stageKV(cur ^ 1);

    // S^T = K Q^T: sacc[n][reg] = S[q = l15][key = kt + n*16 + g*4 + reg]
    f32x4 sacc[4] = {};
    __builtin_amdgcn_s_setprio(1);
#pragma unroll
    for (int n = 0; n < 4; ++n) {
      int key = n * 16 + l15;
#pragma unroll
      for (int kc = 0; kc < 2; ++kc) {
        int kb2 = (kc * 32 + g * 8) * 2;
        bf16x8 kf = *(const bf16x8*)((char*)Ks[cur] + key * 128 + (kb2 ^ ((key & 7) << 4)));
        sacc[n] = __builtin_amdgcn_mfma_f32_16x16x32_bf16(kf, aq[kc], sacc[n], 0, 0, 0);
      }
    }
    __builtin_amdgcn_s_setprio(0);

    // lane-local softmax over 16 keys (log2 units), cross-g reduce only
    float sv[4][4];
    float tm = -1e30f;
#pragma unroll
    for (int n = 0; n < 4; ++n) {
      float4 mb = *(const float4*)&mbias[kt + n * 16 + g4];
      sv[n][0] = sacc[n][0] + mb.x;
      sv[n][1] = sacc[n][1] + mb.y;
      sv[n][2] = sacc[n][2] + mb.z;
      sv[n][3] = sacc[n][3] + mb.w;
      tm = fmaxf(tm, fmaxf(fmaxf(sv[n][0], sv[n][1]), fmaxf(sv[n][2], sv[n][3])));
    }
    tm = fmaxf(tm, __shfl_xor(tm, 16));
    tm = fmaxf(tm, __shfl_xor(tm, 32));

    if (__any(tm - m_run > 11.5f)) {   // defer-max (= e^8 in ln units)
      float mn = fmaxf(m_run, tm);
      float al = exp2v(m_run - mn);
      m_run = mn;
      l_run *= al;
      float ao[4];
#pragma unroll
      for (int j = 0; j < 4; ++j) ao[j] = __shfl(al, g4 + j);
#pragma unroll
      for (int df = 0; df < 4; ++df)
#pragma unroll
        for (int j = 0; j < 4; ++j) o_acc[df][j] *= ao[j];
    }

    float psum = 0.0f;
    u32x2 pk[4];
#pragma unroll
    for (int n = 0; n < 4; ++n) {
      float p0 = exp2v(sv[n][0] - m_run);
      float p1 = exp2v(sv[n][1] - m_run);
      float p2 = exp2v(sv[n][2] - m_run);
      float p3 = exp2v(sv[n][3] - m_run);
      psum += (p0 + p1) + (p2 + p3);
      pk[n][0] = cvt_pk_bf16(p0, p1);
      pk[n][1] = cvt_pk_bf16(p2, p3);
    }
    psum += __shfl_xor(psum, 16);
    psum += __shfl_xor(psum, 32);
    l_run += psum;

    // P -> LDS: row q=l15, 8B chunk per n at key-offset, row-XOR swizzled
    char* prow = pw + l15 * 128;
#pragma unroll
    for (int n = 0; n < 4; ++n)
      *(u32x2*)(prow + ((n * 32 + g * 8) ^ swz)) = pk[n];

    // O += P V
    __builtin_amdgcn_s_setprio(1);
#pragma unroll
    for (int kc = 0; kc < 2; ++kc) {
      int kb2 = (kc * 32 + g * 8) * 2;
      bf16x8 pa = *(const bf16x8*)(prow + ((kc * 64 + g * 16) ^ swz));
#pragma unroll
      for (int df = 0; df < 4; ++df) {
        int d = df * 16 + l15;
        bf16x8 bv = *(const bf16x8*)((char*)Vs[cur] + d * 128 + (kb2 ^ ((d & 7) << 4)));
        o_acc[df] = __builtin_amdgcn_mfma_f32_16x16x32_bf16(pa, bv, o_acc[df], 0, 0, 0);
      }
    }
    __builtin_amdgcn_s_setprio(0);

    wait_vm0_barrier();
    cur ^= 1;
  }

  // finalize: o_acc row j is q-row g*4+j; fetch its l from lane g*4+j
  float inv[4];
#pragma unroll
  for (int j = 0; j < 4; ++j) inv[j] = 1.0f / __shfl(l_run, g4 + j);
  int qrow_base = q0 + w * 16 + g4;
#pragma unroll
  for (int df = 0; df < 4; ++df) {
    int col = h * 64 + df * 16 + l15;
#pragma unroll
    for (int j = 0; j < 4; ++j) {
      int qrow = qrow_base + j;
      ctx[((size_t)(b * 1024 + qrow)) * 1024 + col] = f2bf(o_acc[df][j] * inv[j]);
    }
  }
}

extern "C" void kernel_launch(void* const* d_in, const int* in_sizes, int n_in,
                              void* d_out, int out_size, void* d_ws, size_t ws_size,
                              hipStream_t stream) {
  const float* query = (const float*)d_in[0];
  const float* key   = (const float*)d_in[1];
  const float* value = (const float*)d_in[2];
  const int*   mask  = (const int*)d_in[3];
  const float* Wq = (const float*)d_in[4];
  const float* bq = (const float*)d_in[5];
  const float* Wk = (const float*)d_in[6];
  const float* bk = (const float*)d_in[7];
  const float* Wv = (const float*)d_in[8];
  const float* bv = (const float*)d_in[9];
  const float* Wo = (const float*)d_in[10];
  const float* bo = (const float*)d_in[11];
  const float* ln_g = (const float*)d_in[12];
  const float* ln_b = (const float*)d_in[13];
  float* out = (float*)d_out;

  char* p = (char*)d_ws;
  auto alloc = [&](size_t elems) { ushort* r = (ushort*)p; p += elems * 2; return r; };
  ushort* WqT  = alloc((size_t)1024 * 1024);
  ushort* WkT  = alloc((size_t)1024 * 512);
  ushort* WvT  = alloc((size_t)1024 * 512);
  ushort* WoT  = alloc((size_t)1024 * 1024);
  ushort* qn   = alloc((size_t)4096 * 1024);
  ushort* keyb = alloc((size_t)8192 * 512);
  ushort* valb = alloc((size_t)8192 * 512);
  ushort* Qb   = alloc((size_t)4096 * 1024);
  ushort* Kb   = alloc((size_t)8192 * 1024);
  ushort* Vt   = alloc((size_t)8192 * 1024);
  ushort* ctx  = alloc((size_t)4096 * 1024);
  (void)ws_size; (void)in_sizes; (void)n_in; (void)out_size;

  const float QSCALE = 0.125f * 1.44269504f;  // HD^-0.5 * log2(e), folded into Q

  dim3 blk(256);
  transpose_cast_kernel<<<dim3(16, 16), blk, 0, stream>>>(Wq, WqT, 1024, 1024);
  transpose_cast_kernel<<<dim3(8, 16),  blk, 0, stream>>>(Wk, WkT, 512, 1024);
  transpose_cast_kernel<<<dim3(8, 16),  blk, 0, stream>>>(Wv, WvT, 512, 1024);
  transpose_cast_kernel<<<dim3(16, 16), blk, 0, stream>>>(Wo, WoT, 1024, 1024);
  cast_bf16_kernel<<<dim3(1024), blk, 0, stream>>>((const float4*)key,   (ushort4*)keyb, (8192 * 512) / 4);
  cast_bf16_kernel<<<dim3(1024), blk, 0, stream>>>((const float4*)value, (ushort4*)valb, (8192 * 512) / 4);
  ln_kernel<<<dim3(4096), blk, 0, stream>>>(query, ln_g, ln_b, qn);

  gemm_bt_kernel<0><<<dim3(8, 32), blk, 0, stream>>>(qn,   WqT, bq, Qb, nullptr, 4096, 1024, 1024, QSCALE);
  gemm_bt_kernel<0><<<dim3(8, 64), blk, 0, stream>>>(keyb, WkT, bk, Kb, nullptr, 8192, 1024, 512, 1.0f);
  gemm_bt_kernel<1><<<dim3(8, 64), blk, 0, stream>>>(valb, WvT, bv, Vt, nullptr, 8192, 1024, 512, 1.0f);

  attn_kernel<<<dim3(16, 64), blk, 0, stream>>>(Qb, Kb, Vt, mask, ctx);

  gemm_bt_kernel<2><<<dim3(8, 32), blk, 0, stream>>>(ctx, WoT, bo, out, query, 4096, 1024, 1024, 1.0f);
}

// Round 4
// 163.314 us; speedup vs baseline: 1.4765x; 1.2744x over previous
//
#include <hip/hip_runtime.h>
#include <hip/hip_bf16.h>
#include <stdint.h>

// Problem constants
#define Bn 4
#define LQ 1024
#define LK 2048
#define Dm 1024
#define Hn 16
#define HD 64

typedef __attribute__((ext_vector_type(4))) float f32x4;
typedef __attribute__((ext_vector_type(8))) short bf16x8;
typedef __attribute__((ext_vector_type(2))) uint32_t u32x2;

__device__ __forceinline__ ushort f2bf(float f) {
  union { float f; uint32_t u; } v; v.f = f;
  uint32_t r = v.u + 0x7FFF + ((v.u >> 16) & 1);
  return (ushort)(r >> 16);
}

__device__ __forceinline__ uint32_t cvt_pk_bf16(float lo, float hi) {
  uint32_t r;
  asm("v_cvt_pk_bf16_f32 %0, %1, %2" : "=v"(r) : "v"(lo), "v"(hi));
  return r;
}

__device__ __forceinline__ float exp2v(float x) {  // D = 2^x
  float r;
  asm("v_exp_f32 %0, %1" : "=v"(r) : "v"(x));
  return r;
}

__device__ __forceinline__ void gload16(const void* g, void* lds) {
  __builtin_amdgcn_global_load_lds(
      (const __attribute__((address_space(1))) void*)g,
      (__attribute__((address_space(3))) void*)lds, 16, 0, 0);
}

__device__ __forceinline__ void wait_vm0_barrier() {
  asm volatile("s_waitcnt vmcnt(0)" ::: "memory");
  __builtin_amdgcn_s_barrier();
}

// ---------------- weight transpose + cast: W[K][N] f32 -> Wt[N][K] bf16 ----------------
__global__ __launch_bounds__(256) void transpose_cast_kernel(
    const float* __restrict__ W, ushort* __restrict__ Wt, int K, int N) {
  __shared__ float tile[64][65];
  int k0 = blockIdx.x * 64, n0 = blockIdx.y * 64;
  int tx = threadIdx.x & 63, ty = threadIdx.x >> 6;
#pragma unroll
  for (int i = 0; i < 16; ++i) {
    int r = ty + i * 4;
    tile[r][tx] = W[(size_t)(k0 + r) * N + n0 + tx];
  }
  __syncthreads();
#pragma unroll
  for (int i = 0; i < 16; ++i) {
    int r = ty + i * 4;
    Wt[(size_t)(n0 + r) * K + k0 + tx] = f2bf(tile[tx][r]);
  }
}

// ---------------- elementwise f32 -> bf16 cast ----------------
__global__ __launch_bounds__(256) void cast_bf16_kernel(
    const float4* __restrict__ in, ushort4* __restrict__ out, int n4) {
  int i = blockIdx.x * blockDim.x + threadIdx.x;
  int stride = gridDim.x * blockDim.x;
  for (; i < n4; i += stride) {
    float4 v = in[i];
    out[i] = make_ushort4(f2bf(v.x), f2bf(v.y), f2bf(v.z), f2bf(v.w));
  }
}

// ---------------- LayerNorm over D=1024, f32 in -> bf16 out ----------------
__global__ __launch_bounds__(256) void ln_kernel(
    const float* __restrict__ x, const float* __restrict__ g,
    const float* __restrict__ b, ushort* __restrict__ y) {
  int row = blockIdx.x;
  const float4* xr = (const float4*)(x + (size_t)row * 1024);
  float4 v = xr[threadIdx.x];
  float s1 = v.x + v.y + v.z + v.w;
  float s2 = v.x * v.x + v.y * v.y + v.z * v.z + v.w * v.w;
#pragma unroll
  for (int off = 32; off > 0; off >>= 1) {
    s1 += __shfl_down(s1, off);
    s2 += __shfl_down(s2, off);
  }
  __shared__ float r1[4], r2[4];
  int w = threadIdx.x >> 6, lane = threadIdx.x & 63;
  if (lane == 0) { r1[w] = s1; r2[w] = s2; }
  __syncthreads();
  s1 = r1[0] + r1[1] + r1[2] + r1[3];
  s2 = r2[0] + r2[1] + r2[2] + r2[3];
  float mu = s1 * (1.0f / 1024.0f);
  float var = s2 * (1.0f / 1024.0f) - mu * mu;
  float rstd = rsqrtf(var + 1e-5f);
  float4 gv = ((const float4*)g)[threadIdx.x];
  float4 bv = ((const float4*)b)[threadIdx.x];
  ushort4 o;
  o.x = f2bf((v.x - mu) * rstd * gv.x + bv.x);
  o.y = f2bf((v.y - mu) * rstd * gv.y + bv.y);
  o.z = f2bf((v.z - mu) * rstd * gv.z + bv.z);
  o.w = f2bf((v.w - mu) * rstd * gv.w + bv.w);
  ((ushort4*)(y + (size_t)row * 1024))[threadIdx.x] = o;
}

// ---------------- GEMM: C[M][N] = A[M][K](bf16) @ Bt[N][K]^T(bf16) + bias ----------------
// 512 threads / 8 waves, 128x128 tile, BK=64, XOR-swizzled LDS, 2-phase pipelined.
// EPI 0: bf16 out, value (acc+bias)*osc.  EPI 1: bf16 out scattered to Vt.  EPI 2: f32 + residual.
template <int EPI>
__global__ __launch_bounds__(512) void gemm_bt_kernel(
    const ushort* __restrict__ A, const ushort* __restrict__ Bt,
    const float* __restrict__ bias, void* __restrict__ Cout,
    const float* __restrict__ residual, int M, int N, int K, float osc) {
  __shared__ ushort As[2][128 * 64];
  __shared__ ushort Bs[2][128 * 64];
  const int t = threadIdx.x;
  const int lane = t & 63;
  const int w = t >> 6;
  const int wm = w >> 2, wn = w & 3;   // 2x4 wave grid: 64x32 per wave
  const int m0 = blockIdx.y * 128, n0 = blockIdx.x * 128;
  const int l15 = lane & 15, g = lane >> 4;

  f32x4 acc[4][2] = {};

  // staging: 1024 16B chunks per matrix per K-step; 2 per thread
  const int c0 = t, c1 = t + 512;
  const int r0 = c0 >> 3, x0 = ((c0 & 7) ^ (r0 & 7)) * 8;
  const int r1 = c1 >> 3, x1 = ((c1 & 7) ^ (r1 & 7)) * 8;
  const ushort* Ap0 = A + (size_t)(m0 + r0) * K + x0;
  const ushort* Ap1 = A + (size_t)(m0 + r1) * K + x1;
  const ushort* Bp0 = Bt + (size_t)(n0 + r0) * K + x0;
  const ushort* Bp1 = Bt + (size_t)(n0 + r1) * K + x1;

  auto stage = [&](int buf, int kt) {
    gload16(Ap0 + kt, (char*)As[buf] + c0 * 16);
    gload16(Ap1 + kt, (char*)As[buf] + c1 * 16);
    gload16(Bp0 + kt, (char*)Bs[buf] + c0 * 16);
    gload16(Bp1 + kt, (char*)Bs[buf] + c1 * 16);
  };

  stage(0, 0);
  wait_vm0_barrier();

  int cur = 0;
  for (int kt = 0; kt < K; kt += 64) {
    if (kt + 64 < K) stage(cur ^ 1, kt + 64);
    bf16x8 af[4][2], bfr[2][2];
#pragma unroll
    for (int m = 0; m < 4; ++m) {
      int row = wm * 64 + m * 16 + l15;
#pragma unroll
      for (int kc = 0; kc < 2; ++kc)
        af[m][kc] = *(const bf16x8*)(As[cur] + row * 64 + ((kc * 4 + g) ^ (row & 7)) * 8);
    }
#pragma unroll
    for (int n = 0; n < 2; ++n) {
      int row = wn * 32 + n * 16 + l15;
#pragma unroll
      for (int kc = 0; kc < 2; ++kc)
        bfr[n][kc] = *(const bf16x8*)(Bs[cur] + row * 64 + ((kc * 4 + g) ^ (row & 7)) * 8);
    }
#pragma unroll
    for (int m = 0; m < 4; ++m)
#pragma unroll
      for (int n = 0; n < 2; ++n)
#pragma unroll
        for (int kc = 0; kc < 2; ++kc)
          acc[m][n] = __builtin_amdgcn_mfma_f32_16x16x32_bf16(af[m][kc], bfr[n][kc], acc[m][n], 0, 0, 0);
    wait_vm0_barrier();
    cur ^= 1;
  }

  float bias_v[2];
#pragma unroll
  for (int n = 0; n < 2; ++n) bias_v[n] = bias[n0 + wn * 32 + n * 16 + l15];

#pragma unroll
  for (int m = 0; m < 4; ++m) {
#pragma unroll
    for (int n = 0; n < 2; ++n) {
      int col = n0 + wn * 32 + n * 16 + l15;
      if (EPI == 1) {
        int row_base = m0 + wm * 64 + m * 16 + g * 4;
        int bb = row_base >> 11;        // / 2048
        int key = row_base & 2047;
        int h = col >> 6, hd = col & 63;
        ushort4 pk;
        pk.x = f2bf(acc[m][n][0] + bias_v[n]);
        pk.y = f2bf(acc[m][n][1] + bias_v[n]);
        pk.z = f2bf(acc[m][n][2] + bias_v[n]);
        pk.w = f2bf(acc[m][n][3] + bias_v[n]);
        *(ushort4*)((ushort*)Cout + ((size_t)((bb * 16 + h) * 64 + hd)) * 2048 + key) = pk;
      } else {
#pragma unroll
        for (int j = 0; j < 4; ++j) {
          int row = m0 + wm * 64 + m * 16 + g * 4 + j;
          if (EPI == 0) {
            float v = (acc[m][n][j] + bias_v[n]) * osc;
            ((ushort*)Cout)[(size_t)row * N + col] = f2bf(v);
          } else {
            size_t idx = (size_t)row * N + col;
            ((float*)Cout)[idx] = acc[m][n][j] + bias_v[n] + residual[idx];
          }
        }
      }
    }
  }
}

// ---------------- fused flash attention (swapped QK^T) ----------------
// grid: 512 blocks (XCD-chunked), 512 threads = 8 waves, QBLK=128 (16 q-rows/wave).
// S^T = mfma(K,Q): lane holds full P-row (16 keys) for q = lane&15 -> lane-local softmax.
// Q pre-scaled by 0.125*log2e in projection; exp via raw v_exp_f32 (base-2).
__global__ __launch_bounds__(512) void attn_kernel(
    const ushort* __restrict__ Qb, const ushort* __restrict__ Kb,
    const ushort* __restrict__ Vt, const int* __restrict__ mask,
    ushort* __restrict__ ctx) {
  __shared__ float mbias[2048];       // 8 KB
  __shared__ ushort Ks[2][64 * 64];   // [key][dim], XOR-swizzled rows, dbuf
  __shared__ ushort Vs[2][64 * 64];   // [dim][key], XOR-swizzled rows, dbuf
  __shared__ ushort Ps[8][16 * 64];   // per-wave P tile [qrow][key], swizzled

  const int t = threadIdx.x, lane = t & 63, w = t >> 6;
  const int l15 = lane & 15, g = lane >> 4, g4 = g * 4;
  // XCD-chunked swizzle: 512 blocks, 8 XCDs, chunk=64
  int o = blockIdx.x;
  int logical = (o & 7) * 64 + (o >> 3);
  const int b = logical >> 7;
  const int h = (logical >> 3) & 15;
  const int q0 = (logical & 7) * 128;
  const int* maskp = mask + b * 2048;

  // staging pointers (1 K-chunk + 1 V-chunk per thread per tile)
  const int rA = t >> 3;
  const int xA = ((t & 7) ^ (rA & 7)) * 8;
  const ushort* kp = Kb + ((size_t)(b * 2048 + rA)) * 1024 + h * 64 + xA;
  const ushort* vp = Vt + ((size_t)((b * 16 + h) * 64 + rA)) * 2048 + xA;

  auto stageKV = [&](int buf) {
    gload16(kp, (char*)Ks[buf] + t * 16);
    gload16(vp, (char*)Vs[buf] + t * 16);
  };

  stageKV(0);
  for (int i = t; i < 2048; i += 512) mbias[i] = maskp[i] ? 0.0f : -1e30f;

  // Q fragments (pre-scaled by 0.125*log2e at projection time)
  bf16x8 aq[2];
  {
    int qrow = q0 + w * 16 + l15;
    const ushort* qp = Qb + ((size_t)(b * 1024 + qrow)) * 1024 + h * 64;
    aq[0] = *(const bf16x8*)(qp + g * 8);
    aq[1] = *(const bf16x8*)(qp + 32 + g * 8);
  }

  f32x4 o_acc[4] = {};
  float m_run = -1e30f, l_run = 0.0f;

  wait_vm0_barrier();  // staged tile 0 + mbias fill

  char* pw = (char*)Ps[w];
  const int swz = (l15 & 7) << 4;

  int cur = 0;
  for (int kt = 0; kt < 2048; kt += 64) {
    kp += 64 * 1024;
    vp += 64;
    if (kt + 64 < 2048) stageKV(cur ^ 1);

    // S^T = K Q^T: sacc[n][reg] = S[q = l15][key = kt + n*16 + g*4 + reg]
    f32x4 sacc[4] = {};
    __builtin_amdgcn_s_setprio(1);
#pragma unroll
    for (int n = 0; n < 4; ++n) {
      int key = n * 16 + l15;
#pragma unroll
      for (int kc = 0; kc < 2; ++kc) {
        int kb2 = (kc * 32 + g * 8) * 2;
        bf16x8 kf = *(const bf16x8*)((char*)Ks[cur] + key * 128 + (kb2 ^ ((key & 7) << 4)));
        sacc[n] = __builtin_amdgcn_mfma_f32_16x16x32_bf16(kf, aq[kc], sacc[n], 0, 0, 0);
      }
    }
    __builtin_amdgcn_s_setprio(0);

    // lane-local softmax over 16 keys (log2 units), cross-g reduce only
    float sv[4][4];
    float tm = -1e30f;
#pragma unroll
    for (int n = 0; n < 4; ++n) {
      float4 mb = *(const float4*)&mbias[kt + n * 16 + g4];
      sv[n][0] = sacc[n][0] + mb.x;
      sv[n][1] = sacc[n][1] + mb.y;
      sv[n][2] = sacc[n][2] + mb.z;
      sv[n][3] = sacc[n][3] + mb.w;
      tm = fmaxf(tm, fmaxf(fmaxf(sv[n][0], sv[n][1]), fmaxf(sv[n][2], sv[n][3])));
    }
    tm = fmaxf(tm, __shfl_xor(tm, 16));
    tm = fmaxf(tm, __shfl_xor(tm, 32));

    if (__any(tm - m_run > 11.5f)) {   // defer-max (= e^8 in ln units)
      float mn = fmaxf(m_run, tm);
      float al = exp2v(m_run - mn);
      m_run = mn;
      l_run *= al;
      float ao[4];
#pragma unroll
      for (int j = 0; j < 4; ++j) ao[j] = __shfl(al, g4 + j);
#pragma unroll
      for (int df = 0; df < 4; ++df)
#pragma unroll
        for (int j = 0; j < 4; ++j) o_acc[df][j] *= ao[j];
    }

    float psum = 0.0f;
    u32x2 pk[4];
#pragma unroll
    for (int n = 0; n < 4; ++n) {
      float p0 = exp2v(sv[n][0] - m_run);
      float p1 = exp2v(sv[n][1] - m_run);
      float p2 = exp2v(sv[n][2] - m_run);
      float p3 = exp2v(sv[n][3] - m_run);
      psum += (p0 + p1) + (p2 + p3);
      pk[n][0] = cvt_pk_bf16(p0, p1);
      pk[n][1] = cvt_pk_bf16(p2, p3);
    }
    psum += __shfl_xor(psum, 16);
    psum += __shfl_xor(psum, 32);
    l_run += psum;

    // P -> LDS: row q=l15, 8B chunk per n at key-offset, row-XOR swizzled
    char* prow = pw + l15 * 128;
#pragma unroll
    for (int n = 0; n < 4; ++n)
      *(u32x2*)(prow + ((n * 32 + g * 8) ^ swz)) = pk[n];

    // O += P V
    __builtin_amdgcn_s_setprio(1);
#pragma unroll
    for (int kc = 0; kc < 2; ++kc) {
      int kb2 = (kc * 32 + g * 8) * 2;
      bf16x8 pa = *(const bf16x8*)(prow + ((kc * 64 + g * 16) ^ swz));
#pragma unroll
      for (int df = 0; df < 4; ++df) {
        int d = df * 16 + l15;
        bf16x8 bv = *(const bf16x8*)((char*)Vs[cur] + d * 128 + (kb2 ^ ((d & 7) << 4)));
        o_acc[df] = __builtin_amdgcn_mfma_f32_16x16x32_bf16(pa, bv, o_acc[df], 0, 0, 0);
      }
    }
    __builtin_amdgcn_s_setprio(0);

    wait_vm0_barrier();
    cur ^= 1;
  }

  // finalize: o_acc row j is q-row g*4+j; fetch its l from lane g*4+j
  float inv[4];
#pragma unroll
  for (int j = 0; j < 4; ++j) inv[j] = 1.0f / __shfl(l_run, g4 + j);
  int qrow_base = q0 + w * 16 + g4;
#pragma unroll
  for (int df = 0; df < 4; ++df) {
    int col = h * 64 + df * 16 + l15;
#pragma unroll
    for (int j = 0; j < 4; ++j) {
      int qrow = qrow_base + j;
      ctx[((size_t)(b * 1024 + qrow)) * 1024 + col] = f2bf(o_acc[df][j] * inv[j]);
    }
  }
}

extern "C" void kernel_launch(void* const* d_in, const int* in_sizes, int n_in,
                              void* d_out, int out_size, void* d_ws, size_t ws_size,
                              hipStream_t stream) {
  const float* query = (const float*)d_in[0];
  const float* key   = (const float*)d_in[1];
  const float* value = (const float*)d_in[2];
  const int*   mask  = (const int*)d_in[3];
  const float* Wq = (const float*)d_in[4];
  const float* bq = (const float*)d_in[5];
  const float* Wk = (const float*)d_in[6];
  const float* bk = (const float*)d_in[7];
  const float* Wv = (const float*)d_in[8];
  const float* bv = (const float*)d_in[9];
  const float* Wo = (const float*)d_in[10];
  const float* bo = (const float*)d_in[11];
  const float* ln_g = (const float*)d_in[12];
  const float* ln_b = (const float*)d_in[13];
  float* out = (float*)d_out;

  char* p = (char*)d_ws;
  auto alloc = [&](size_t elems) { ushort* r = (ushort*)p; p += elems * 2; return r; };
  ushort* WqT  = alloc((size_t)1024 * 1024);
  ushort* WkT  = alloc((size_t)1024 * 512);
  ushort* WvT  = alloc((size_t)1024 * 512);
  ushort* WoT  = alloc((size_t)1024 * 1024);
  ushort* qn   = alloc((size_t)4096 * 1024);
  ushort* keyb = alloc((size_t)8192 * 512);
  ushort* valb = alloc((size_t)8192 * 512);
  ushort* Qb   = alloc((size_t)4096 * 1024);
  ushort* Kb   = alloc((size_t)8192 * 1024);
  ushort* Vt   = alloc((size_t)8192 * 1024);
  ushort* ctx  = alloc((size_t)4096 * 1024);
  (void)ws_size; (void)in_sizes; (void)n_in; (void)out_size;

  const float QSCALE = 0.125f * 1.44269504f;  // HD^-0.5 * log2(e), folded into Q

  dim3 blk(256);
  dim3 blk5(512);
  transpose_cast_kernel<<<dim3(16, 16), blk, 0, stream>>>(Wq, WqT, 1024, 1024);
  transpose_cast_kernel<<<dim3(8, 16),  blk, 0, stream>>>(Wk, WkT, 512, 1024);
  transpose_cast_kernel<<<dim3(8, 16),  blk, 0, stream>>>(Wv, WvT, 512, 1024);
  transpose_cast_kernel<<<dim3(16, 16), blk, 0, stream>>>(Wo, WoT, 1024, 1024);
  cast_bf16_kernel<<<dim3(1024), blk, 0, stream>>>((const float4*)key,   (ushort4*)keyb, (8192 * 512) / 4);
  cast_bf16_kernel<<<dim3(1024), blk, 0, stream>>>((const float4*)value, (ushort4*)valb, (8192 * 512) / 4);
  ln_kernel<<<dim3(4096), blk, 0, stream>>>(query, ln_g, ln_b, qn);

  gemm_bt_kernel<0><<<dim3(8, 32), blk5, 0, stream>>>(qn,   WqT, bq, Qb, nullptr, 4096, 1024, 1024, QSCALE);
  gemm_bt_kernel<0><<<dim3(8, 64), blk5, 0, stream>>>(keyb, WkT, bk, Kb, nullptr, 8192, 1024, 512, 1.0f);
  gemm_bt_kernel<1><<<dim3(8, 64), blk5, 0, stream>>>(valb, WvT, bv, Vt, nullptr, 8192, 1024, 512, 1.0f);

  attn_kernel<<<dim3(512), blk5, 0, stream>>>(Qb, Kb, Vt, mask, ctx);

  gemm_bt_kernel<2><<<dim3(8, 32), blk5, 0, stream>>>(ctx, WoT, bo, out, query, 4096, 1024, 1024, 1.0f);
}